// Round 4
// baseline (94.127 us; speedup 1.0000x reference)
//
#include <hip/hip_runtime.h>
#include <hip/hip_bf16.h>

typedef __attribute__((ext_vector_type(4))) short bf16x4;   // 4 bf16 = 2 VGPR
typedef __attribute__((ext_vector_type(4))) float f32x4;
typedef __attribute__((ext_vector_type(4))) int i32x4;

static __device__ inline f32x4 mfma16(bf16x4 a, bf16x4 b, f32x4 c) {
  return __builtin_amdgcn_mfma_f32_16x16x16bf16_1k(a, b, c, 0, 0, 0);
}

static __device__ inline ushort f2bf(float f) {
  union { float f; unsigned int i; } v; v.f = f;
  unsigned int x = v.i;
  return (ushort)((x + 0x7FFFu + ((x >> 16) & 1u)) >> 16);  // RNE
}

// ---------------------------------------------------------------------------
// C[M x 128] = (A[M x 128] @ W[128 x 128] + bias) * alpha, M = 8192.
// A f32 or bf16 (template); W/bias f32; C bf16 or f32 (template).
// grid: 1024 blocks x 256 threads; each wave computes one 16x16 tile.
// ---------------------------------------------------------------------------
template <bool A_IS_F32, bool OUT_F32>
__global__ __launch_bounds__(256) void gemm_proj(
    const void* __restrict__ A_, const float* __restrict__ W,
    const float* __restrict__ bias, void* __restrict__ C_, float alpha) {
  const int tid = threadIdx.x;
  const int l = tid & 63, w = tid >> 6;
  const int lm = l & 15, g = l >> 4;
  const int tile = blockIdx.x * 4 + w;      // 0..4095
  const int mt = tile >> 3, nt = tile & 7;  // 512 x 8 tiles
  const int row = mt * 16 + lm;
  const int col = nt * 16 + lm;

  f32x4 acc = {0.f, 0.f, 0.f, 0.f};
#pragma unroll
  for (int ks = 0; ks < 8; ++ks) {
    bf16x4 a;
    if constexpr (A_IS_F32) {
      const float* A = (const float*)A_;
      f32x4 av = *(const f32x4*)(A + (size_t)row * 128 + ks * 16 + g * 4);
      a[0] = (short)f2bf(av[0]); a[1] = (short)f2bf(av[1]);
      a[2] = (short)f2bf(av[2]); a[3] = (short)f2bf(av[3]);
    } else {
      const ushort* A = (const ushort*)A_;
      a = *(const bf16x4*)(A + (size_t)row * 128 + ks * 16 + g * 4);
    }
    const float* wp = W + (size_t)(ks * 16 + g * 4) * 128 + col;
    bf16x4 b;
    b[0] = (short)f2bf(wp[0]);   b[1] = (short)f2bf(wp[128]);
    b[2] = (short)f2bf(wp[256]); b[3] = (short)f2bf(wp[384]);
    acc = mfma16(a, b, acc);
  }
  const float bv = bias[col];
#pragma unroll
  for (int r = 0; r < 4; ++r) {
    float v = (acc[r] + bv) * alpha;
    if constexpr (OUT_F32)
      ((float*)C_)[(size_t)(mt * 16 + g * 4 + r) * 128 + col] = v;
    else
      ((ushort*)C_)[(size_t)(mt * 16 + g * 4 + r) * 128 + col] = f2bf(v);
  }
}

// ---------------------------------------------------------------------------
// Fused graph attention: one WG per (b, 16-row tile), 8 waves = 8 heads.
// Sweep 64 col tiles of 16; adj(int32)/edge(f32) double-buffered in LDS.
// ---------------------------------------------------------------------------
#define ST 20  // LDS row stride (elements) for 16-wide tiles -> 2-way max

__global__ __launch_bounds__(512) void attn_kernel(
    const ushort* __restrict__ Qs, const ushort* __restrict__ Ks,
    const ushort* __restrict__ Vs, const int* __restrict__ adj,
    const float* __restrict__ edge, const float* __restrict__ Wep,
    const float* __restrict__ bep, ushort* __restrict__ AO) {
  __shared__ int adj_lds[2][16 * ST];
  __shared__ float edge_lds[2][16 * ST];

  const int tid = threadIdx.x;
  const int l = tid & 63, h = tid >> 6;
  const int lm = l & 15, g = l >> 4;
  const int b = blockIdx.x >> 6;
  const int m0 = (blockIdx.x & 63) * 16;

  const float Weh = Wep[h];
  const float beh = bep[h];

  // Q fragment (1/sqrt(hd) folded in at projection): B-frag of S^T = K.Q^T
  // lane holds Q[m0+lm][k = 4g + 0..3] of head h
  const bf16x4 qf = *(const bf16x4*)(Qs + ((size_t)b * 1024 + m0 + lm) * 128 + h * 16 + g * 4);

  const int*   adj_b  = adj  + (size_t)b * 1024 * 1024 + (size_t)m0 * 1024;
  const float* edge_b = edge + (size_t)b * 1024 * 1024 + (size_t)m0 * 1024;

  // loader roles: wave0 -> adj (16B/lane), wave1 -> edge (16B/lane)
  const bool ld_adj  = (tid < 64);
  const bool ld_edge = (tid >= 64 && tid < 128);
  const int ar = (tid & 63) >> 2, ac = (tid & 3) * 4;

  // prologue: stage tile 0
  if (ld_adj)
    *(i32x4*)&adj_lds[0][ar * ST + ac] = *(const i32x4*)(adj_b + (size_t)ar * 1024 + ac);
  if (ld_edge)
    *(f32x4*)&edge_lds[0][ar * ST + ac] = *(const f32x4*)(edge_b + (size_t)ar * 1024 + ac);

  float mmax = -1e30f;
  float lsum = 0.f;
  f32x4 oacc = {0.f, 0.f, 0.f, 0.f};

  for (int ct = 0; ct < 64; ++ct) {
    __syncthreads();  // buf[ct&1] staged; prior reads of buf[ct&1^1] done
    const int buf = ct & 1;
    const int n0 = ct * 16;
    const bool pf = (ct < 63);

    // prefetch next tile into registers (LDS write after compute)
    i32x4 pa; f32x4 pe;
    if (pf && ld_adj)  pa = *(const i32x4*)(adj_b + (size_t)ar * 1024 + n0 + 16 + ac);
    if (pf && ld_edge) pe = *(const f32x4*)(edge_b + (size_t)ar * 1024 + n0 + 16 + ac);

    // K fragment: A-frag of S^T: lane holds K[n0+lm][4g+0..3]
    const bf16x4 kf = *(const bf16x4*)(Ks + ((size_t)b * 1024 + n0 + lm) * 128 + h * 16 + g * 4);
    // V fragment: A-frag of O^T = V^T.P^T: lane holds V[n0+4g+i][d=lm]
    bf16x4 vf;
    {
      const ushort* vp = Vs + ((size_t)b * 1024 + n0 + g * 4) * 128 + h * 16 + lm;
      vf[0] = (short)vp[0];   vf[1] = (short)vp[128];
      vf[2] = (short)vp[256]; vf[3] = (short)vp[384];
    }

    // S^T tile: lane l, reg r -> (n = n0 + 4g + r, m = m0 + lm)
    f32x4 st = {0.f, 0.f, 0.f, 0.f};
    st = mfma16(kf, qf, st);

    const i32x4 a4 = *(const i32x4*)&adj_lds[buf][lm * ST + g * 4];
    const f32x4 e4 = *(const f32x4*)&edge_lds[buf][lm * ST + g * 4];

    float s0 = (a4[0] == 0) ? -INFINITY : (st[0] + e4[0] * Weh + beh);
    float s1 = (a4[1] == 0) ? -INFINITY : (st[1] + e4[1] * Weh + beh);
    float s2 = (a4[2] == 0) ? -INFINITY : (st[2] + e4[2] * Weh + beh);
    float s3 = (a4[3] == 0) ? -INFINITY : (st[3] + e4[3] * Weh + beh);

    // per-m (column) max of tile: 4 regs + lanes {l^16, l^32}
    float tmax = fmaxf(fmaxf(s0, s1), fmaxf(s2, s3));
    tmax = fmaxf(tmax, __shfl_xor(tmax, 16, 64));
    tmax = fmaxf(tmax, __shfl_xor(tmax, 32, 64));

    const float mnew = fmaxf(mmax, fmaxf(tmax, -1e30f));
    const float alpha = __expf(mmax - mnew);
    const float p0 = __expf(s0 - mnew);
    const float p1 = __expf(s1 - mnew);
    const float p2 = __expf(s2 - mnew);
    const float p3 = __expf(s3 - mnew);
    float ts = p0 + p1 + p2 + p3;
    ts += __shfl_xor(ts, 16, 64);
    ts += __shfl_xor(ts, 32, 64);
    lsum = lsum * alpha + ts;
    mmax = mnew;
    oacc[0] *= alpha; oacc[1] *= alpha; oacc[2] *= alpha; oacc[3] *= alpha;

    // P^T in S^T's C/D layout == B-frag layout of the PV mfma: no shuffles.
    bf16x4 pfrag;
    pfrag[0] = (short)f2bf(p0); pfrag[1] = (short)f2bf(p1);
    pfrag[2] = (short)f2bf(p2); pfrag[3] = (short)f2bf(p3);
    oacc = mfma16(vf, pfrag, oacc);  // O^T[d = 4g+r][m = lm]

    if (pf && ld_adj)  *(i32x4*)&adj_lds[buf ^ 1][ar * ST + ac] = pa;
    if (pf && ld_edge) *(f32x4*)&edge_lds[buf ^ 1][ar * ST + ac] = pe;
  }

  const float inv = 1.0f / lsum;
  bf16x4 ov;
  ov[0] = (short)f2bf(oacc[0] * inv);
  ov[1] = (short)f2bf(oacc[1] * inv);
  ov[2] = (short)f2bf(oacc[2] * inv);
  ov[3] = (short)f2bf(oacc[3] * inv);
  *(bf16x4*)(AO + ((size_t)b * 1024 + m0 + lm) * 128 + h * 16 + g * 4) = ov;
}

extern "C" void kernel_launch(void* const* d_in, const int* in_sizes, int n_in,
                              void* d_out, int out_size, void* d_ws, size_t ws_size,
                              hipStream_t stream) {
  const float* x   = (const float*)d_in[0];
  const int*   adj = (const int*)d_in[1];
  const float* ew  = (const float*)d_in[2];
  const float* Wq  = (const float*)d_in[3];
  const float* bq  = (const float*)d_in[4];
  const float* Wk  = (const float*)d_in[5];
  const float* bk  = (const float*)d_in[6];
  const float* Wv  = (const float*)d_in[7];
  const float* bv  = (const float*)d_in[8];
  const float* Wo  = (const float*)d_in[9];
  const float* bo  = (const float*)d_in[10];
  const float* We  = (const float*)d_in[11];
  const float* be  = (const float*)d_in[12];

  const size_t MN = (size_t)8 * 1024 * 128;  // 1M elements
  ushort* Qs = (ushort*)d_ws;
  ushort* Ks = Qs + MN;
  ushort* Vs = Ks + MN;
  ushort* AO = Vs + MN;

  // scale = sqrt(hd) = 4 -> fold 0.25 into Q
  gemm_proj<true,  false><<<1024, 256, 0, stream>>>(x, Wq, bq, Qs, 0.25f);
  gemm_proj<true,  false><<<1024, 256, 0, stream>>>(x, Wk, bk, Ks, 1.0f);
  gemm_proj<true,  false><<<1024, 256, 0, stream>>>(x, Wv, bv, Vs, 1.0f);
  attn_kernel<<<512, 512, 0, stream>>>(Qs, Ks, Vs, adj, ew, We, be, AO);
  gemm_proj<false, true><<<1024, 256, 0, stream>>>(AO, Wo, bo, d_out, 1.0f);
}